// Round 13
// baseline (192.199 us; speedup 1.0000x reference)
//
#include <hip/hip_runtime.h>
#include <hip/hip_bf16.h>

typedef __bf16 bf16;
typedef __bf16 bf16x8 __attribute__((ext_vector_type(8)));
typedef __bf16 bf16x4 __attribute__((ext_vector_type(4)));
typedef float f32x4 __attribute__((ext_vector_type(4)));

#define CDIM 1280

static __device__ __forceinline__ f32x4 mfma16(bf16x8 a, bf16x8 b, f32x4 c) {
  return __builtin_amdgcn_mfma_f32_16x16x32_bf16(a, b, c, 0, 0, 0);
}

static __device__ __forceinline__ void gload_lds(const bf16* g, bf16* l) {
  __builtin_amdgcn_global_load_lds(
      (const __attribute__((address_space(1))) void*)g,
      (__attribute__((address_space(3))) void*)l, 16, 0, 0);
}

static __device__ __forceinline__ float fexp2(float x) {
#if __has_builtin(__builtin_amdgcn_exp2f)
  return __builtin_amdgcn_exp2f(x);
#else
  return __expf(x * 0.6931471805599453f);
#endif
}

// ---- fused f32 -> bf16 conversion for hidden + 4 weights ----
__global__ __launch_bounds__(256) void cvt_all(const float* __restrict__ h,
                                               const float* __restrict__ wq,
                                               const float* __restrict__ wk,
                                               const float* __restrict__ wv,
                                               const float* __restrict__ wo,
                                               bf16* __restrict__ hb, bf16* __restrict__ wqb,
                                               bf16* __restrict__ wkb, bf16* __restrict__ wvb,
                                               bf16* __restrict__ wob) {
  int id = blockIdx.x * 256 + threadIdx.x;  // float4 index, total 2949120
  const float* src; bf16* dst; int off;
  if (id < 1310720) { src = h; dst = hb; off = id; }
  else {
    int t = id - 1310720;
    int w = t / 409600; off = t % 409600;
    src = (w == 0) ? wq : (w == 1) ? wk : (w == 2) ? wv : wo;
    dst = (w == 0) ? wqb : (w == 1) ? wkb : (w == 2) ? wvb : wob;
  }
  float4 v = reinterpret_cast<const float4*>(src)[off];
  bf16x4 o;
  o[0] = (bf16)v.x; o[1] = (bf16)v.y; o[2] = (bf16)v.z; o[3] = (bf16)v.w;
  reinterpret_cast<bf16x4*>(dst)[off] = o;
}

// ---- fused QKV projection v13: BK=32, 3-buffer, 2-ahead prefetch,
// counted vmcnt(4) certified before raw s_barrier (R12-attn proven pattern) ----
__global__ __launch_bounds__(256) void qkv_gemm(const bf16* __restrict__ X,
                                                const bf16* __restrict__ Wq,
                                                const bf16* __restrict__ Wk,
                                                const bf16* __restrict__ Wv,
                                                const float* __restrict__ mask,
                                                bf16* __restrict__ Qb,
                                                bf16* __restrict__ Kb,
                                                bf16* __restrict__ Vt) {
  __shared__ bf16 SM[24576];   // 48 KB: A[3][4096] | B[3][4096]; T reuses first 32 KB
  const int tid = threadIdx.x, lane = tid & 63, wv = tid >> 6;
  const int lr = lane & 15, lg = lane >> 4;
  // bijective XCD-chunked swizzle: nwg = 960 = 8 * 120
  const int flat = blockIdx.y * 30 + blockIdx.x;
  const int swz = (flat & 7) * 120 + (flat >> 3);
  const int xb = swz % 30, by = swz / 30;
  const int wsel = xb / 10;            // 0=Q 1=K 2=V
  const int cb = (xb % 10) * 128;
  const bf16* W = (wsel == 0) ? Wq : (wsel == 1) ? Wk : Wv;
  const int strow = tid >> 2, stchk = tid & 3;     // 64 rows x 4 chunks per half
  const int ssw = (strow & 3);                     // stage-side swizzle key
  const int fsw = (lr & 3);                        // read-side swizzle key

  // 4 gload_lds per thread per stage() -> vmcnt counts 4 per stage
  auto stage = [&](int kt, int buf) {
#pragma unroll
    for (int i = 0; i < 2; ++i) {
      const int row = i * 64 + strow;
      gload_lds(X + (size_t)(by * 128 + row) * CDIM + kt * 32 + (stchk ^ ssw) * 8,
                &SM[buf * 4096 + i * 2048 + tid * 8]);
      gload_lds(W + (size_t)(cb + row) * CDIM + kt * 32 + (stchk ^ ssw) * 8,
                &SM[12288 + buf * 4096 + i * 2048 + tid * 8]);
    }
  };

  f32x4 acc[4][4] = {};
  stage(0, 0);
  stage(1, 1);
  asm volatile("s_waitcnt vmcnt(4)" ::: "memory");  // stage0 landed; stage1 in flight
  __builtin_amdgcn_sched_barrier(0);
  __builtin_amdgcn_s_barrier();

  int cur = 0;
  for (int kt = 0; kt < 40; ++kt) {
    if (kt < 38) {
      int nb = cur + 2; if (nb >= 3) nb -= 3;
      stage(kt + 2, nb);   // 2 ahead; that buffer was last read in step kt-1
    }
    bf16x8 a[4], b[4];
#pragma unroll
    for (int i = 0; i < 4; ++i) {
      const int ra = (wv >> 1) * 64 + i * 16 + lr;
      const int rb = (wv & 1) * 64 + i * 16 + lr;
      a[i] = *(const bf16x8*)&SM[cur * 4096 + ra * 32 + (lg ^ fsw) * 8];
      b[i] = *(const bf16x8*)&SM[12288 + cur * 4096 + rb * 32 + (lg ^ fsw) * 8];
    }
#pragma unroll
    for (int i = 0; i < 4; ++i)
#pragma unroll
      for (int j = 0; j < 4; ++j)
        acc[i][j] = mfma16(a[i], b[j], acc[i][j]);
    if (kt < 39) {
      // certify own stage(kt+1) loads landed BEFORE barrier; stage(kt+2) in flight
      if (kt < 38) asm volatile("s_waitcnt vmcnt(4)" ::: "memory");
      else         asm volatile("s_waitcnt vmcnt(0)" ::: "memory");
      __builtin_amdgcn_sched_barrier(0);
      __builtin_amdgcn_s_barrier();
    }
    ++cur; if (cur >= 3) cur = 0;
  }

  if (wsel == 2) {
    // ---- V epilogue: gate, permute keys, LDS-transpose, coalesced store ----
    __builtin_amdgcn_s_barrier();   // all compute reads done before T overwrite
    bf16* T = &SM[0];               // first 32 KB as T[128col][128row]
#pragma unroll
    for (int i = 0; i < 4; ++i)
#pragma unroll
      for (int r = 0; r < 4; ++r) {
        const int lrow = (wv >> 1) * 64 + i * 16 + lg * 4 + r;   // local key row
        const int row = by * 128 + lrow;
        const float g = (row >= 2048) ? mask[row - 2048] : 1.0f;
        const int rb = lrow >> 6, kpos = lrow & 63;
        const int jp = (kpos & 32) + ((kpos >> 2) & 3) * 8 + ((kpos >> 4) & 1) * 4 + (kpos & 3);
#pragma unroll
        for (int j = 0; j < 4; ++j) {
          const int col = (wv & 1) * 64 + j * 16 + lr;           // local channel
          T[col * 128 + ((rb * 64 + jp) ^ ((col & 7) << 3))] = (bf16)(acc[i][j][r] * g);
        }
      }
    __syncthreads();
#pragma unroll
    for (int q = 0; q < 8; ++q) {
      const int col = (tid >> 4) + q * 16;
      const int rc = tid & 15, rb = rc >> 3, rc8 = rc & 7;
      bf16x8 vv = *(const bf16x8*)&T[col * 128 + rb * 64 + ((rc8 ^ (col & 7)) << 3)];
      const int gcol = cb + col, hh = gcol >> 6, d = gcol & 63;
      const int kb64 = by * 2 + rb;
      const int br = kb64 >> 5, bb = (kb64 >> 4) & 1, kt = kb64 & 15;
      *(bf16x8*)&Vt[(size_t)(((br * 40 + bb * 20 + hh) * 16 + kt) * 64 + d) * 64 + rc8 * 8] = vv;
    }
  } else {
    const int rbase = by * 128 + (wv >> 1) * 64;
    const int cbase = cb + (wv & 1) * 64;
    bf16* Y = (wsel == 0) ? Qb : Kb;
    const bool gated = (wsel == 1);
#pragma unroll
    for (int i = 0; i < 4; ++i)
#pragma unroll
      for (int r = 0; r < 4; ++r) {
        const int row = rbase + i * 16 + lg * 4 + r;
        const float g = (gated && row >= 2048) ? mask[row - 2048] : 1.0f;
#pragma unroll
        for (int j = 0; j < 4; ++j)
          Y[(size_t)row * CDIM + cbase + j * 16 + lr] = (bf16)(acc[i][j][r] * g);
      }
  }
}

// ---- flash attention (R12, frozen): 3-buffer, counted vmcnt, ones-MFMA l,
// local-pm vote, in-register P via permuted-V layout ----
__global__ __launch_bounds__(256) void attn_kernel(const bf16* __restrict__ Q,
                                                   const bf16* __restrict__ K,
                                                   const bf16* __restrict__ Vt,
                                                   bf16* __restrict__ Mg) {
  __shared__ bf16 Kl[3][64 * 64];   // 24 KB
  __shared__ bf16 Vl[3][64 * 64];   // 24 KB
  const int tid = threadIdx.x, lane = tid & 63, wv = tid >> 6;
  const int lr = lane & 15, lg = lane >> 4;
  // bijective XCD-chunked swizzle (nwg = 1280, 1280 % 8 == 0)
  const int bid = blockIdx.x;
  const int sb = (bid & 7) * 160 + (bid >> 3);
  const int qt = sb & 31, hh = (sb >> 5) % 20, b = sb / 640;
  const int qrow = b * 2048 + qt * 64 + wv * 16;
  const int strow = tid >> 3, stchk = tid & 7;
  const int sw = lr & 7;

  const bf16* Kb0 = K + (size_t)(b * 1024) * CDIM + hh * 64;
  const bf16* Vb0 = Vt + (size_t)(b * 20 + hh) * 65536;

  // Q fragments (B-operand: col=q=lr over this wave's 16 rows), exp2-domain scale
  bf16x8 qf0, qf1;
  {
    const float SL2E = 0.125f * 1.4426950408889634f;
    const bf16* qp = Q + (size_t)(qrow + lr) * CDIM + hh * 64 + lg * 8;
    bf16x8 r0 = *(const bf16x8*)qp;
    bf16x8 r1 = *(const bf16x8*)(qp + 32);
#pragma unroll
    for (int j = 0; j < 8; ++j) {
      qf0[j] = (bf16)((float)r0[j] * SL2E);
      qf1[j] = (bf16)((float)r1[j] * SL2E);
    }
  }
  bf16x8 ones8;
#pragma unroll
  for (int j = 0; j < 8; ++j) ones8[j] = (bf16)1.0f;

  // per-thread loads per stage() call = 4 gload_lds -> vmcnt counts 4/stage
  auto stage = [&](int t, int buf) {
    const int br = t >> 4, kt = t & 15;
    const bf16* Kp = Kb0 + (size_t)br * 2048 * CDIM;
    const bf16* Vp = Vb0 + (size_t)br * 40 * 65536;
#pragma unroll
    for (int i = 0; i < 2; ++i) {
      const int row = i * 32 + strow;
      gload_lds(Kp + (size_t)(kt * 64 + row) * CDIM + (stchk ^ (row & 7)) * 8,
                &Kl[buf][(i * 256 + tid) * 8]);
      gload_lds(Vp + kt * 4096 + row * 64 + (stchk ^ (row & 7)) * 8,
                &Vl[buf][(i * 256 + tid) * 8]);
    }
  };

  float m = -INFINITY;
  f32x4 lacc = {};
  f32x4 O[4] = {};
  f32x4 Ofin[4] = {};

  stage(0, 0);
  stage(1, 1);
  asm volatile("s_waitcnt vmcnt(4)" ::: "memory");  // tile0 landed; tile1 in flight
  __builtin_amdgcn_sched_barrier(0);
  __builtin_amdgcn_s_barrier();

  int cur = 0;
  for (int t = 0; t < 32; ++t) {
    if (t < 30) {
      int nb = cur + 2; if (nb >= 3) nb -= 3;
      stage(t + 2, nb);   // 2 tiles ahead; its buffer was last read in tile t-1
    }

    // S^T[key][q] = K . Q^T   (lane owns q = lr; keys kb*16 + lg*4 + r)
    f32x4 z[4];
    __builtin_amdgcn_s_setprio(1);
#pragma unroll
    for (int kb = 0; kb < 4; ++kb) {
      const int row = kb * 16 + lr;
      bf16x8 k0 = *(const bf16x8*)&Kl[cur][row * 64 + (lg ^ sw) * 8];
      bf16x8 k1 = *(const bf16x8*)&Kl[cur][row * 64 + ((4 + lg) ^ sw) * 8];
      f32x4 zz = {};
      zz = mfma16(k0, qf0, zz);
      zz = mfma16(k1, qf1, zz);
      z[kb] = zz;
    }
    __builtin_amdgcn_s_setprio(0);

    // local max (tree, depth 4); vote on LOCAL pm (equivalent under __all)
    float t0 = fmaxf(fmaxf(z[0][0], z[0][1]), fmaxf(z[0][2], z[0][3]));
    float t1 = fmaxf(fmaxf(z[1][0], z[1][1]), fmaxf(z[1][2], z[1][3]));
    float t2 = fmaxf(fmaxf(z[2][0], z[2][1]), fmaxf(z[2][2], z[2][3]));
    float t3 = fmaxf(fmaxf(z[3][0], z[3][1]), fmaxf(z[3][2], z[3][3]));
    float pml = fmaxf(fmaxf(t0, t1), fmaxf(t2, t3));

    float p[16];
    if (__all(pml <= m + 8.f)) {          // hot path: no cross-lane ops
#pragma unroll
      for (int kb = 0; kb < 4; ++kb)
#pragma unroll
        for (int r = 0; r < 4; ++r) p[kb * 4 + r] = fexp2(z[kb][r] - m);
    } else {                              // rare: full reduce + rescale
      float pm = fmaxf(pml, __shfl_xor(pml, 16, 64));
      pm = fmaxf(pm, __shfl_xor(pm, 32, 64));
      const float mn = fmaxf(m, pm);
      const float al = fexp2(m - mn);
#pragma unroll
      for (int kb = 0; kb < 4; ++kb)
#pragma unroll
        for (int r = 0; r < 4; ++r) p[kb * 4 + r] = fexp2(z[kb][r] - mn);
      m = mn;
      lacc[0] *= al; lacc[1] *= al; lacc[2] *= al; lacc[3] *= al;
#pragma unroll
      for (int dt = 0; dt < 4; ++dt) {
        O[dt][0] *= al; O[dt][1] *= al; O[dt][2] *= al; O[dt][3] *= al;
      }
    }

    // P stays in registers as PV B-fragment (key-permuted): pb_s[e] = p[s*8+e]
    bf16x8 pb0, pb1;
#pragma unroll
    for (int e = 0; e < 8; ++e) { pb0[e] = (bf16)p[e]; pb1[e] = (bf16)p[8 + e]; }

    // O^T[d][q] += V . P ; l via ones-MFMA
    __builtin_amdgcn_s_setprio(1);
#pragma unroll
    for (int dt = 0; dt < 4; ++dt) {
      const int row = dt * 16 + lr;
      bf16x8 v0 = *(const bf16x8*)&Vl[cur][row * 64 + (lg ^ sw) * 8];
      bf16x8 v1 = *(const bf16x8*)&Vl[cur][row * 64 + ((4 + lg) ^ sw) * 8];
      O[dt] = mfma16(v0, pb0, O[dt]);
      O[dt] = mfma16(v1, pb1, O[dt]);
    }
    lacc = mfma16(ones8, pb0, lacc);
    lacc = mfma16(ones8, pb1, lacc);
    __builtin_amdgcn_s_setprio(0);

    if (t == 15 || t == 31) {  // end of branch: merge with 1/l (in-lane, q = lr)
      const float invl = 1.0f / lacc[0];
#pragma unroll
      for (int dt = 0; dt < 4; ++dt) {
        Ofin[dt][0] += O[dt][0] * invl; Ofin[dt][1] += O[dt][1] * invl;
        Ofin[dt][2] += O[dt][2] * invl; Ofin[dt][3] += O[dt][3] * invl;
      }
      if (t == 15) {
        m = -INFINITY;
        lacc = f32x4{};
#pragma unroll
        for (int dt = 0; dt < 4; ++dt) O[dt] = f32x4{};
      }
    }

    if (t < 31) {
      // wait only for tile t+1's stage (4 per-wave loads); t+2's stay in flight
      if (t < 30) asm volatile("s_waitcnt vmcnt(4)" ::: "memory");
      else        asm volatile("s_waitcnt vmcnt(0)" ::: "memory");
      __builtin_amdgcn_sched_barrier(0);
      __builtin_amdgcn_s_barrier();
    }
    ++cur; if (cur >= 3) cur = 0;
  }

  // store: lane holds q = qrow+lr, d = dt*16 + lg*4 + 0..3 -> b64 stores
#pragma unroll
  for (int dt = 0; dt < 4; ++dt) {
    bf16x4 o4;
    o4[0] = (bf16)Ofin[dt][0]; o4[1] = (bf16)Ofin[dt][1];
    o4[2] = (bf16)Ofin[dt][2]; o4[3] = (bf16)Ofin[dt][3];
    *(bf16x4*)&Mg[(size_t)(qrow + lr) * CDIM + hh * 64 + dt * 16 + lg * 4] = o4;
  }
}

// ---- final projection v13: BK=32, 3-buffer counted-vmcnt, XCD swizzle ----
__global__ __launch_bounds__(256) void out_gemm(const bf16* __restrict__ X,
                                                const bf16* __restrict__ W,
                                                const float* __restrict__ bias,
                                                float* __restrict__ Y) {
  __shared__ bf16 SM[24576];   // 48 KB: A[3][4096] | B[3][4096]
  const int tid = threadIdx.x, lane = tid & 63, wv = tid >> 6;
  const int lr = lane & 15, lg = lane >> 4;
  // bijective XCD-chunked swizzle: nwg = 320 = 8 * 40
  const int flat = blockIdx.y * 10 + blockIdx.x;
  const int swz = (flat & 7) * 40 + (flat >> 3);
  const int cb = (swz % 10) * 128, by = swz / 10;
  const int strow = tid >> 2, stchk = tid & 3;
  const int ssw = (strow & 3);
  const int fsw = (lr & 3);

  auto stage = [&](int kt, int buf) {
#pragma unroll
    for (int i = 0; i < 2; ++i) {
      const int row = i * 64 + strow;
      gload_lds(X + (size_t)(by * 128 + row) * CDIM + kt * 32 + (stchk ^ ssw) * 8,
                &SM[buf * 4096 + i * 2048 + tid * 8]);
      gload_lds(W + (size_t)(cb + row) * CDIM + kt * 32 + (stchk ^ ssw) * 8,
                &SM[12288 + buf * 4096 + i * 2048 + tid * 8]);
    }
  };

  f32x4 acc[4][4] = {};
  stage(0, 0);
  stage(1, 1);
  asm volatile("s_waitcnt vmcnt(4)" ::: "memory");
  __builtin_amdgcn_sched_barrier(0);
  __builtin_amdgcn_s_barrier();

  int cur = 0;
  for (int kt = 0; kt < 40; ++kt) {
    if (kt < 38) {
      int nb = cur + 2; if (nb >= 3) nb -= 3;
      stage(kt + 2, nb);
    }
    bf16x8 a[4], b[4];
#pragma unroll
    for (int i = 0; i < 4; ++i) {
      const int ra = (wv >> 1) * 64 + i * 16 + lr;
      const int rb = (wv & 1) * 64 + i * 16 + lr;
      a[i] = *(const bf16x8*)&SM[cur * 4096 + ra * 32 + (lg ^ fsw) * 8];
      b[i] = *(const bf16x8*)&SM[12288 + cur * 4096 + rb * 32 + (lg ^ fsw) * 8];
    }
#pragma unroll
    for (int i = 0; i < 4; ++i)
#pragma unroll
      for (int j = 0; j < 4; ++j)
        acc[i][j] = mfma16(a[i], b[j], acc[i][j]);
    if (kt < 39) {
      if (kt < 38) asm volatile("s_waitcnt vmcnt(4)" ::: "memory");
      else         asm volatile("s_waitcnt vmcnt(0)" ::: "memory");
      __builtin_amdgcn_sched_barrier(0);
      __builtin_amdgcn_s_barrier();
    }
    ++cur; if (cur >= 3) cur = 0;
  }
  const int rbase = by * 128 + (wv >> 1) * 64;
  const int cbase = cb + (wv & 1) * 64;
#pragma unroll
  for (int i = 0; i < 4; ++i)
#pragma unroll
    for (int r = 0; r < 4; ++r) {
      const int row = rbase + i * 16 + lg * 4 + r;
#pragma unroll
      for (int j = 0; j < 4; ++j) {
        const int col = cbase + j * 16 + lr;
        Y[(size_t)row * CDIM + col] = acc[i][j][r] + bias[col];
      }
    }
}

extern "C" void kernel_launch(void* const* d_in, const int* in_sizes, int n_in,
                              void* d_out, int out_size, void* d_ws, size_t ws_size,
                              hipStream_t stream) {
  const float* hidden = (const float*)d_in[0];
  const float* mask   = (const float*)d_in[1];
  const float* Wq     = (const float*)d_in[2];
  const float* Wk     = (const float*)d_in[3];
  const float* Wv     = (const float*)d_in[4];
  const float* Wo     = (const float*)d_in[5];
  const float* bo     = (const float*)d_in[6];
  float* out = (float*)d_out;

  char* ws = (char*)d_ws;
  bf16* hb  = (bf16*)(ws);             // 4096x1280 (aliased as Mg after projections)
  bf16* wqb = (bf16*)(ws + 10485760);
  bf16* wkb = (bf16*)(ws + 13762560);
  bf16* wvb = (bf16*)(ws + 17039360);
  bf16* wob = (bf16*)(ws + 20316160);
  bf16* Qb  = (bf16*)(ws + 23592960);  // 4096x1280
  bf16* Kb  = (bf16*)(ws + 34078720);  // 4096x1280 (bg rows 0..2047, face gated 2048..4095)
  bf16* Vt  = (bf16*)(ws + 44564480);  // [80 bh][16 kt][64 d][64 j] permuted V, gated
  bf16* Mg  = hb;

  cvt_all<<<dim3(11520), 256, 0, stream>>>(hidden, Wq, Wk, Wv, Wo, hb, wqb, wkb, wvb, wob);
  qkv_gemm<<<dim3(30, 32), 256, 0, stream>>>(hb, wqb, wkb, wvb, mask, Qb, Kb, Vt);
  attn_kernel<<<dim3(1280), 256, 0, stream>>>(Qb, Kb, Vt, Mg);
  out_gemm<<<dim3(10, 32), 256, 0, stream>>>(Mg, wob, bo, out);
}

// Round 14
// 181.419 us; speedup vs baseline: 1.0594x; 1.0594x over previous
//
#include <hip/hip_runtime.h>
#include <hip/hip_bf16.h>

typedef __bf16 bf16;
typedef __bf16 bf16x8 __attribute__((ext_vector_type(8)));
typedef __bf16 bf16x4 __attribute__((ext_vector_type(4)));
typedef float f32x4 __attribute__((ext_vector_type(4)));

#define CDIM 1280

static __device__ __forceinline__ f32x4 mfma16(bf16x8 a, bf16x8 b, f32x4 c) {
  return __builtin_amdgcn_mfma_f32_16x16x32_bf16(a, b, c, 0, 0, 0);
}

static __device__ __forceinline__ void gload_lds(const bf16* g, bf16* l) {
  __builtin_amdgcn_global_load_lds(
      (const __attribute__((address_space(1))) void*)g,
      (__attribute__((address_space(3))) void*)l, 16, 0, 0);
}

static __device__ __forceinline__ float fexp2(float x) {
#if __has_builtin(__builtin_amdgcn_exp2f)
  return __builtin_amdgcn_exp2f(x);
#else
  return __expf(x * 0.6931471805599453f);
#endif
}

// ---- fused f32 -> bf16 conversion for hidden + 4 weights ----
__global__ __launch_bounds__(256) void cvt_all(const float* __restrict__ h,
                                               const float* __restrict__ wq,
                                               const float* __restrict__ wk,
                                               const float* __restrict__ wv,
                                               const float* __restrict__ wo,
                                               bf16* __restrict__ hb, bf16* __restrict__ wqb,
                                               bf16* __restrict__ wkb, bf16* __restrict__ wvb,
                                               bf16* __restrict__ wob) {
  int id = blockIdx.x * 256 + threadIdx.x;  // float4 index, total 2949120
  const float* src; bf16* dst; int off;
  if (id < 1310720) { src = h; dst = hb; off = id; }
  else {
    int t = id - 1310720;
    int w = t / 409600; off = t % 409600;
    src = (w == 0) ? wq : (w == 1) ? wk : (w == 2) ? wv : wo;
    dst = (w == 0) ? wqb : (w == 1) ? wkb : (w == 2) ? wvb : wob;
  }
  float4 v = reinterpret_cast<const float4*>(src)[off];
  bf16x4 o;
  o[0] = (bf16)v.x; o[1] = (bf16)v.y; o[2] = (bf16)v.z; o[3] = (bf16)v.w;
  reinterpret_cast<bf16x4*>(dst)[off] = o;
}

// ---- fused QKV projection (R12 best): BK=32 dbuf 32KB, XOR-swizzled, XCD swizzle ----
__global__ __launch_bounds__(256) void qkv_gemm(const bf16* __restrict__ X,
                                                const bf16* __restrict__ Wq,
                                                const bf16* __restrict__ Wk,
                                                const bf16* __restrict__ Wv,
                                                const float* __restrict__ mask,
                                                bf16* __restrict__ Qb,
                                                bf16* __restrict__ Kb,
                                                bf16* __restrict__ Vt) {
  __shared__ bf16 SM[16384];   // 32 KB: Al[2][4096] | Bl[2][4096]; reused as T
  const int tid = threadIdx.x, lane = tid & 63, wv = tid >> 6;
  const int lr = lane & 15, lg = lane >> 4;
  // bijective XCD-chunked swizzle: nwg = 960 = 8 * 120
  const int flat = blockIdx.y * 30 + blockIdx.x;
  const int swz = (flat & 7) * 120 + (flat >> 3);
  const int xb = swz % 30, by = swz / 30;
  const int wsel = xb / 10;            // 0=Q 1=K 2=V
  const int cb = (xb % 10) * 128;
  const bf16* W = (wsel == 0) ? Wq : (wsel == 1) ? Wk : Wv;
  const int strow = tid >> 2, stchk = tid & 3;     // 64 rows x 4 chunks per half
  const int ssw = (strow & 3);                     // stage-side swizzle key
  const int fsw = (lr & 3);                        // read-side swizzle key

  auto stage = [&](int kt, int buf) {
#pragma unroll
    for (int i = 0; i < 2; ++i) {
      const int row = i * 64 + strow;
      gload_lds(X + (size_t)(by * 128 + row) * CDIM + kt * 32 + (stchk ^ ssw) * 8,
                &SM[buf * 4096 + i * 2048 + tid * 8]);
      gload_lds(W + (size_t)(cb + row) * CDIM + kt * 32 + (stchk ^ ssw) * 8,
                &SM[8192 + buf * 4096 + i * 2048 + tid * 8]);
    }
  };

  f32x4 acc[4][4] = {};
  stage(0, 0);
  __syncthreads();
  for (int kt = 0; kt < 40; ++kt) {
    const int cur = kt & 1;
    if (kt < 39) stage(kt + 1, cur ^ 1);   // overlaps compute below
    bf16x8 a[4], b[4];
#pragma unroll
    for (int i = 0; i < 4; ++i) {
      const int ra = (wv >> 1) * 64 + i * 16 + lr;
      const int rb = (wv & 1) * 64 + i * 16 + lr;
      a[i] = *(const bf16x8*)&SM[cur * 4096 + ra * 32 + (lg ^ fsw) * 8];
      b[i] = *(const bf16x8*)&SM[8192 + cur * 4096 + rb * 32 + (lg ^ fsw) * 8];
    }
#pragma unroll
    for (int i = 0; i < 4; ++i)
#pragma unroll
      for (int j = 0; j < 4; ++j)
        acc[i][j] = mfma16(a[i], b[j], acc[i][j]);
    __syncthreads();   // stage(kt+1) drained; buf[cur] free for overwrite
  }

  if (wsel == 2) {
    // ---- V epilogue: gate, permute keys, LDS-transpose, coalesced store ----
    bf16* T = &SM[0];   // all 32 KB as T[128col][128row]
#pragma unroll
    for (int i = 0; i < 4; ++i)
#pragma unroll
      for (int r = 0; r < 4; ++r) {
        const int lrow = (wv >> 1) * 64 + i * 16 + lg * 4 + r;   // local key row
        const int row = by * 128 + lrow;
        const float g = (row >= 2048) ? mask[row - 2048] : 1.0f;
        const int rb = lrow >> 6, kpos = lrow & 63;
        const int jp = (kpos & 32) + ((kpos >> 2) & 3) * 8 + ((kpos >> 4) & 1) * 4 + (kpos & 3);
#pragma unroll
        for (int j = 0; j < 4; ++j) {
          const int col = (wv & 1) * 64 + j * 16 + lr;           // local channel
          T[col * 128 + ((rb * 64 + jp) ^ ((col & 7) << 3))] = (bf16)(acc[i][j][r] * g);
        }
      }
    __syncthreads();
#pragma unroll
    for (int q = 0; q < 8; ++q) {
      const int col = (tid >> 4) + q * 16;
      const int rc = tid & 15, rb = rc >> 3, rc8 = rc & 7;
      bf16x8 vv = *(const bf16x8*)&T[col * 128 + rb * 64 + ((rc8 ^ (col & 7)) << 3)];
      const int gcol = cb + col, hh = gcol >> 6, d = gcol & 63;
      const int kb64 = by * 2 + rb;
      const int br = kb64 >> 5, bb = (kb64 >> 4) & 1, kt = kb64 & 15;
      *(bf16x8*)&Vt[(size_t)(((br * 40 + bb * 20 + hh) * 16 + kt) * 64 + d) * 64 + rc8 * 8] = vv;
    }
  } else {
    const int rbase = by * 128 + (wv >> 1) * 64;
    const int cbase = cb + (wv & 1) * 64;
    bf16* Y = (wsel == 0) ? Qb : Kb;
    const bool gated = (wsel == 1);
#pragma unroll
    for (int i = 0; i < 4; ++i)
#pragma unroll
      for (int r = 0; r < 4; ++r) {
        const int row = rbase + i * 16 + lg * 4 + r;
        const float g = (gated && row >= 2048) ? mask[row - 2048] : 1.0f;
#pragma unroll
        for (int j = 0; j < 4; ++j)
          Y[(size_t)row * CDIM + cbase + j * 16 + lr] = (bf16)(acc[i][j][r] * g);
      }
  }
}

// ---- flash attention (R11 best): 2-buffer 32KB dbuf, ones-MFMA l, local-pm
// vote, in-register P via permuted-V layout, swapped QK^T, exp2 softmax ----
__global__ __launch_bounds__(256) void attn_kernel(const bf16* __restrict__ Q,
                                                   const bf16* __restrict__ K,
                                                   const bf16* __restrict__ Vt,
                                                   bf16* __restrict__ Mg) {
  __shared__ bf16 Kl[2][64 * 64];
  __shared__ bf16 Vl[2][64 * 64];
  const int tid = threadIdx.x, lane = tid & 63, wv = tid >> 6;
  const int lr = lane & 15, lg = lane >> 4;
  // bijective XCD-chunked swizzle (nwg = 1280, 1280 % 8 == 0)
  const int bid = blockIdx.x;
  const int sb = (bid & 7) * 160 + (bid >> 3);
  const int qt = sb & 31, hh = (sb >> 5) % 20, b = sb / 640;
  const int qrow = b * 2048 + qt * 64 + wv * 16;
  const int strow = tid >> 3, stchk = tid & 7;
  const int sw = lr & 7;

  const bf16* Kb0 = K + (size_t)(b * 1024) * CDIM + hh * 64;
  const bf16* Vb0 = Vt + (size_t)(b * 20 + hh) * 65536;

  // Q fragments (B-operand: col=q=lr over this wave's 16 rows), exp2-domain scale
  bf16x8 qf0, qf1;
  {
    const float SL2E = 0.125f * 1.4426950408889634f;
    const bf16* qp = Q + (size_t)(qrow + lr) * CDIM + hh * 64 + lg * 8;
    bf16x8 r0 = *(const bf16x8*)qp;
    bf16x8 r1 = *(const bf16x8*)(qp + 32);
#pragma unroll
    for (int j = 0; j < 8; ++j) {
      qf0[j] = (bf16)((float)r0[j] * SL2E);
      qf1[j] = (bf16)((float)r1[j] * SL2E);
    }
  }
  bf16x8 ones8;
#pragma unroll
  for (int j = 0; j < 8; ++j) ones8[j] = (bf16)1.0f;

  auto stage = [&](int t, int buf) {
    const int br = t >> 4, kt = t & 15;
    const bf16* Kp = Kb0 + (size_t)br * 2048 * CDIM;
    const bf16* Vp = Vb0 + (size_t)br * 40 * 65536;
#pragma unroll
    for (int i = 0; i < 2; ++i) {
      const int row = i * 32 + strow;
      gload_lds(Kp + (size_t)(kt * 64 + row) * CDIM + (stchk ^ (row & 7)) * 8,
                &Kl[buf][(i * 256 + tid) * 8]);
      gload_lds(Vp + kt * 4096 + row * 64 + (stchk ^ (row & 7)) * 8,
                &Vl[buf][(i * 256 + tid) * 8]);
    }
  };

  float m = -INFINITY;
  f32x4 lacc = {};          // l via ones-MFMA: all 4 rows equal Sum_k P[k][q]
  f32x4 O[4] = {};
  f32x4 Ofin[4] = {};

  stage(0, 0);
  __syncthreads();

  for (int t = 0; t < 32; ++t) {
    const int cur = t & 1;
    if (t < 31) stage(t + 1, cur ^ 1);  // issue-early: latency hides under compute

    // S^T[key][q] = K . Q^T   (lane owns q = lr; keys kb*16 + lg*4 + r)
    f32x4 z[4];
    __builtin_amdgcn_s_setprio(1);
#pragma unroll
    for (int kb = 0; kb < 4; ++kb) {
      const int row = kb * 16 + lr;
      bf16x8 k0 = *(const bf16x8*)&Kl[cur][row * 64 + (lg ^ sw) * 8];
      bf16x8 k1 = *(const bf16x8*)&Kl[cur][row * 64 + ((4 + lg) ^ sw) * 8];
      f32x4 zz = {};
      zz = mfma16(k0, qf0, zz);
      zz = mfma16(k1, qf1, zz);
      z[kb] = zz;
    }
    __builtin_amdgcn_s_setprio(0);

    // local max (tree, depth 4); vote on LOCAL pm — __all ANDs across all 64
    // lanes, so this is exactly equivalent to voting on the reduced max.
    float t0 = fmaxf(fmaxf(z[0][0], z[0][1]), fmaxf(z[0][2], z[0][3]));
    float t1 = fmaxf(fmaxf(z[1][0], z[1][1]), fmaxf(z[1][2], z[1][3]));
    float t2 = fmaxf(fmaxf(z[2][0], z[2][1]), fmaxf(z[2][2], z[2][3]));
    float t3 = fmaxf(fmaxf(z[3][0], z[3][1]), fmaxf(z[3][2], z[3][3]));
    float pml = fmaxf(fmaxf(t0, t1), fmaxf(t2, t3));

    float p[16];
    if (__all(pml <= m + 8.f)) {          // hot path: no cross-lane ops at all
#pragma unroll
      for (int kb = 0; kb < 4; ++kb)
#pragma unroll
        for (int r = 0; r < 4; ++r) p[kb * 4 + r] = fexp2(z[kb][r] - m);
    } else {                              // rare: full reduce + rescale
      float pm = fmaxf(pml, __shfl_xor(pml, 16, 64));
      pm = fmaxf(pm, __shfl_xor(pm, 32, 64));
      const float mn = fmaxf(m, pm);
      const float al = fexp2(m - mn);
#pragma unroll
      for (int kb = 0; kb < 4; ++kb)
#pragma unroll
        for (int r = 0; r < 4; ++r) p[kb * 4 + r] = fexp2(z[kb][r] - mn);
      m = mn;
      lacc[0] *= al; lacc[1] *= al; lacc[2] *= al; lacc[3] *= al;
#pragma unroll
      for (int dt = 0; dt < 4; ++dt) {
        O[dt][0] *= al; O[dt][1] *= al; O[dt][2] *= al; O[dt][3] *= al;
      }
    }

    // P stays in registers as PV B-fragment (key-permuted): pb_s[e] = p[s*8+e]
    bf16x8 pb0, pb1;
#pragma unroll
    for (int e = 0; e < 8; ++e) { pb0[e] = (bf16)p[e]; pb1[e] = (bf16)p[8 + e]; }

    // O^T[d][q] += V . P ; l accumulated by ones-MFMA (replaces rs reduction)
    __builtin_amdgcn_s_setprio(1);
#pragma unroll
    for (int dt = 0; dt < 4; ++dt) {
      const int row = dt * 16 + lr;
      bf16x8 v0 = *(const bf16x8*)&Vl[cur][row * 64 + (lg ^ sw) * 8];
      bf16x8 v1 = *(const bf16x8*)&Vl[cur][row * 64 + ((4 + lg) ^ sw) * 8];
      O[dt] = mfma16(v0, pb0, O[dt]);
      O[dt] = mfma16(v1, pb1, O[dt]);
    }
    lacc = mfma16(ones8, pb0, lacc);
    lacc = mfma16(ones8, pb1, lacc);
    __builtin_amdgcn_s_setprio(0);

    if (t == 15 || t == 31) {  // end of branch: merge with 1/l (in-lane, q = lr)
      const float invl = 1.0f / lacc[0];
#pragma unroll
      for (int dt = 0; dt < 4; ++dt) {
        Ofin[dt][0] += O[dt][0] * invl; Ofin[dt][1] += O[dt][1] * invl;
        Ofin[dt][2] += O[dt][2] * invl; Ofin[dt][3] += O[dt][3] * invl;
      }
      if (t == 15) {
        m = -INFINITY;
        lacc = f32x4{};
#pragma unroll
        for (int dt = 0; dt < 4; ++dt) O[dt] = f32x4{};
      }
    }
    __syncthreads();  // staged tile t+1 ready; buf[cur] free for overwrite
  }

  // store: lane holds q = qrow+lr, d = dt*16 + lg*4 + 0..3 -> b64 stores
#pragma unroll
  for (int dt = 0; dt < 4; ++dt) {
    bf16x4 o4;
    o4[0] = (bf16)Ofin[dt][0]; o4[1] = (bf16)Ofin[dt][1];
    o4[2] = (bf16)Ofin[dt][2]; o4[3] = (bf16)Ofin[dt][3];
    *(bf16x4*)&Mg[(size_t)(qrow + lr) * CDIM + hh * 64 + dt * 16 + lg * 4] = o4;
  }
}

// ---- final projection (R12 best): BK=32 dbuf 32KB + swizzle + XCD swizzle ----
__global__ __launch_bounds__(256) void out_gemm(const bf16* __restrict__ X,
                                                const bf16* __restrict__ W,
                                                const float* __restrict__ bias,
                                                float* __restrict__ Y) {
  __shared__ bf16 SM[16384];   // Al[2][4096] | Bl[2][4096]
  const int tid = threadIdx.x, lane = tid & 63, wv = tid >> 6;
  const int lr = lane & 15, lg = lane >> 4;
  // bijective XCD-chunked swizzle: nwg = 320 = 8 * 40
  const int flat = blockIdx.y * 10 + blockIdx.x;
  const int swz = (flat & 7) * 40 + (flat >> 3);
  const int cb = (swz % 10) * 128, by = swz / 10;
  const int strow = tid >> 2, stchk = tid & 3;
  const int ssw = (strow & 3);
  const int fsw = (lr & 3);

  auto stage = [&](int kt, int buf) {
#pragma unroll
    for (int i = 0; i < 2; ++i) {
      const int row = i * 64 + strow;
      gload_lds(X + (size_t)(by * 128 + row) * CDIM + kt * 32 + (stchk ^ ssw) * 8,
                &SM[buf * 4096 + i * 2048 + tid * 8]);
      gload_lds(W + (size_t)(cb + row) * CDIM + kt * 32 + (stchk ^ ssw) * 8,
                &SM[8192 + buf * 4096 + i * 2048 + tid * 8]);
    }
  };

  f32x4 acc[4][4] = {};
  stage(0, 0);
  __syncthreads();
  for (int kt = 0; kt < 40; ++kt) {
    const int cur = kt & 1;
    if (kt < 39) stage(kt + 1, cur ^ 1);
    bf16x8 a[4], b[4];
#pragma unroll
    for (int i = 0; i < 4; ++i) {
      const int ra = (wv >> 1) * 64 + i * 16 + lr;
      const int rb = (wv & 1) * 64 + i * 16 + lr;
      a[i] = *(const bf16x8*)&SM[cur * 4096 + ra * 32 + (lg ^ fsw) * 8];
      b[i] = *(const bf16x8*)&SM[8192 + cur * 4096 + rb * 32 + (lg ^ fsw) * 8];
    }
#pragma unroll
    for (int i = 0; i < 4; ++i)
#pragma unroll
      for (int j = 0; j < 4; ++j)
        acc[i][j] = mfma16(a[i], b[j], acc[i][j]);
    __syncthreads();
  }
  const int rbase = by * 128 + (wv >> 1) * 64;
  const int cbase = cb + (wv & 1) * 64;
#pragma unroll
  for (int i = 0; i < 4; ++i)
#pragma unroll
    for (int r = 0; r < 4; ++r) {
      const int row = rbase + i * 16 + lg * 4 + r;
#pragma unroll
      for (int j = 0; j < 4; ++j) {
        const int col = cbase + j * 16 + lr;
        Y[(size_t)row * CDIM + col] = acc[i][j][r] + bias[col];
      }
    }
}

extern "C" void kernel_launch(void* const* d_in, const int* in_sizes, int n_in,
                              void* d_out, int out_size, void* d_ws, size_t ws_size,
                              hipStream_t stream) {
  const float* hidden = (const float*)d_in[0];
  const float* mask   = (const float*)d_in[1];
  const float* Wq     = (const float*)d_in[2];
  const float* Wk     = (const float*)d_in[3];
  const float* Wv     = (const float*)d_in[4];
  const float* Wo     = (const float*)d_in[5];
  const float* bo     = (const float*)d_in[6];
  float* out = (float*)d_out;

  char* ws = (char*)d_ws;
  bf16* hb  = (bf16*)(ws);             // 4096x1280 (aliased as Mg after projections)
  bf16* wqb = (bf16*)(ws + 10485760);
  bf16* wkb = (bf16*)(ws + 13762560);
  bf16* wvb = (bf16*)(ws + 17039360);
  bf16* wob = (bf16*)(ws + 20316160);
  bf16* Qb  = (bf16*)(ws + 23592960);  // 4096x1280
  bf16* Kb  = (bf16*)(ws + 34078720);  // 4096x1280 (bg rows 0..2047, face gated 2048..4095)
  bf16* Vt  = (bf16*)(ws + 44564480);  // [80 bh][16 kt][64 d][64 j] permuted V, gated
  bf16* Mg  = hb;

  cvt_all<<<dim3(11520), 256, 0, stream>>>(hidden, Wq, Wk, Wv, Wo, hb, wqb, wkb, wvb, wob);
  qkv_gemm<<<dim3(30, 32), 256, 0, stream>>>(hb, wqb, wkb, wvb, mask, Qb, Kb, Vt);
  attn_kernel<<<dim3(1280), 256, 0, stream>>>(Qb, Kb, Vt, Mg);
  out_gemm<<<dim3(10, 32), 256, 0, stream>>>(Mg, wob, bo, out);
}